// Round 5
// baseline (252.963 us; speedup 1.0000x reference)
//
#include <hip/hip_runtime.h>
#include <hip/hip_bf16.h>
#include <string.h>

// Problem constants (B=8, S=4096, H=768, L=256, ATT_HID=1024)
#define M_TOK 32768   // B*S
#define H_DIM 768
#define AH    1024
#define NSEG  2048    // B*L
#define LCAP  192     // aggregate LDS token-list capacity (binomial mean 16, max ~40)
#define NKT   12      // K tiles per n-tile (768/64)

typedef __attribute__((ext_vector_type(8))) __bf16 bf16x8;
typedef __attribute__((ext_vector_type(4))) float f32x4;

// Fast tanh: 1 - 2/(exp(2x)+1). Saturates correctly; ~1e-5 rel err.
__device__ __forceinline__ float tanh_fast(float x) {
  float e = __expf(2.0f * x);
  return 1.0f - 2.0f * __builtin_amdgcn_rcpf(e + 1.0f);
}

// ---------------------------------------------------------------------------
// K0: prep = W1 transpose+convert only (fp32 [768,1024] -> W1t bf16 [1024,768]).
// The X->bf16 conversion pass is GONE: attn reg-stages A from fp32 X with
// in-register cvt, aggregate gathers fp32 X directly.
__global__ __launch_bounds__(256) void prep_kernel(
    const float* __restrict__ W1, __hip_bfloat16* __restrict__ W1t) {
  __shared__ float tile[32][33];
  int nt = blockIdx.x & 31, ktile = blockIdx.x >> 5;
  int n0 = nt * 32, k0 = ktile * 32;
  int tx = threadIdx.x & 31, ty = threadIdx.x >> 5;  // ty 0..7
  for (int r = ty; r < 32; r += 8)
    tile[r][tx] = W1[(size_t)(k0 + r) * AH + n0 + tx];
  __syncthreads();
  for (int r = ty; r < 32; r += 8)
    W1t[(size_t)(n0 + r) * H_DIM + k0 + tx] = __float2bfloat16(tile[tx][r]);
}

// ---------------------------------------------------------------------------
// K1: 256x256 tile, BK=64, 8 waves (2M x 4N). Grid 256 = 1 block/CU; each
// block computes TWO n-tiles (np0, np0+256) as one flat 24-K-tile loop with a
// mid-epilogue. A-operand is REG-STAGED from fp32 X: phase A issues 8 float4
// loads (oldest) + 4 B gload_lds (newest); phase C WAITV(4) -> cvt bf16 ->
// 4x ds_write_b128 into buf P^1; phase D ends WAITV(0) (B issued 3 phases
// earlier, effectively landed). Gray-code quadrant order reuses half the
// frags. XOR-granule swizzle (granule g of row r at physical g^(r&7)) via
// pre-swizzled addressing + linear LDS dest: measured SQ_LDS_BANK_CONFLICT=0.
#define WAITV(N) asm volatile("s_waitcnt vmcnt(" #N ")" ::: "memory")
#define WAITL0   asm volatile("s_waitcnt lgkmcnt(0)" ::: "memory")

__global__ __launch_bounds__(512, 2) void attn_score_kernel(
    const float* __restrict__ Xf,
    const __hip_bfloat16* __restrict__ W1tg, const float* __restrict__ b1g,
    const float* __restrict__ W2g, float* __restrict__ scores2) {
  __shared__ __align__(16) __bf16 As[2][256 * 64];   // 64 KB
  __shared__ __align__(16) __bf16 Bs[2][256 * 64];   // 64 KB

  const int tid = threadIdx.x;
  const int bid = blockIdx.x;
  const int xcd = bid & 7;
  const int sq  = bid >> 3;                 // 0..31
  const int m0  = (xcd * 16 + (sq >> 1)) * 256;   // 128 m-tiles
  const int np0 = (sq & 1) * 512;                 // n-pair base: {0,512}
  const int lane = tid & 63;
  const int wave = tid >> 6;                // 0..7
  const int wm   = wave >> 2;               // 0..1 (M half)
  const int wx   = wave & 3;                // 0..3 (N quarter)
  const int ml   = lane & 15;
  const int lh   = lane >> 4;               // 0..3

  const __bf16* W  = (const __bf16*)W1tg;

  // Staging: op covers 64 lds rows; thread t -> lds row (t>>3), dest granule
  // (t&7), swizzled source column ((t&7)^(row&7))*8.
  const int lr   = tid >> 3;                // 0..63
  const int scol = ((tid & 7) ^ (lr & 7)) << 3;

  int aRow[4], bRow[4];
#pragma unroll
  for (int q = 0; q < 4; ++q) {
    aRow[q] = m0 + ((q & 1) << 7) + ((q >> 1) << 6) + lr;
    int lrow = (q << 6) + lr;
    bRow[q] = np0 + (((lrow >> 5) & 3) << 6) + ((lrow >> 7) << 5) + (lrow & 31);
  }

  f32x4 acc[8][4];
#pragma unroll
  for (int i = 0; i < 8; ++i)
#pragma unroll
    for (int j = 0; j < 4; ++j) acc[i][j] = (f32x4)0.f;

  bf16x8 af[4][2], bfr[2][2];
  float4 ald[4][2];   // in-flight A fp32 (statically indexed only)

  // b1/W2 preload for BOTH n-tiles; drained below so loop vmcnt stays exact.
  float b1v[2][4], w2v[2][4];
#pragma unroll
  for (int sd = 0; sd < 2; ++sd)
#pragma unroll
    for (int nf = 0; nf < 4; ++nf) {
      int n = np0 + sd * 256 + wx * 64 + nf * 16 + ml;
      b1v[sd][nf] = b1g[n];
      w2v[sd][nf] = W2g[n];
    }
  WAITV(0);   // "memory" clobber also pins the loads above this point

  // --- staging helpers ---
#define LOAD_A(q, kt)                                                          \
  {                                                                            \
    const float* ga = Xf + (size_t)aRow[q] * H_DIM + (kt) + scol;              \
    ald[q][0] = *(const float4*)ga;                                            \
    ald[q][1] = *(const float4*)(ga + 4);                                      \
  }
#define WRITE_A(q, buf)                                                        \
  {                                                                            \
    union { bf16x8 v; __hip_bfloat16 h[8]; } u_;                               \
    u_.h[0] = __float2bfloat16(ald[q][0].x);                                   \
    u_.h[1] = __float2bfloat16(ald[q][0].y);                                   \
    u_.h[2] = __float2bfloat16(ald[q][0].z);                                   \
    u_.h[3] = __float2bfloat16(ald[q][0].w);                                   \
    u_.h[4] = __float2bfloat16(ald[q][1].x);                                   \
    u_.h[5] = __float2bfloat16(ald[q][1].y);                                   \
    u_.h[6] = __float2bfloat16(ald[q][1].z);                                   \
    u_.h[7] = __float2bfloat16(ald[q][1].w);                                   \
    *(bf16x8*)&As[buf][(q) * 4096 + tid * 8] = u_.v;                           \
  }
#define STAGE_B(q, buf, kt, nsh)                                               \
  __builtin_amdgcn_global_load_lds(                                            \
      (const __attribute__((address_space(1))) void*)(W +                      \
          (size_t)(bRow[q] + (nsh)) * H_DIM + (kt) + scol),                    \
      (__attribute__((address_space(3))) void*)&Bs[buf][(q) * 4096 + tid * 8], \
      16, 0, 0)

#define DSRA(MH, P)                                                            \
  _Pragma("unroll") for (int lf = 0; lf < 4; ++lf) {                           \
    int ra = ((MH) << 7) + (wm << 6) + (lf << 4) + ml;                         \
    _Pragma("unroll") for (int kk = 0; kk < 2; ++kk) {                         \
      int ph = ((kk << 2) + lh) ^ (ml & 7);                                    \
      af[lf][kk] = *(const bf16x8*)&As[P][(ra << 6) + (ph << 3)];              \
    }                                                                          \
  }
#define DSRB(NH, P)                                                            \
  _Pragma("unroll") for (int jj = 0; jj < 2; ++jj) {                           \
    int rb = ((NH) << 7) + (wx << 5) + (jj << 4) + ml;                         \
    _Pragma("unroll") for (int kk = 0; kk < 2; ++kk) {                         \
      int ph = ((kk << 2) + lh) ^ (ml & 7);                                    \
      bfr[jj][kk] = *(const bf16x8*)&Bs[P][(rb << 6) + (ph << 3)];             \
    }                                                                          \
  }
// kk-outer: 8 independent MFMA chains per sub-cluster.
#define MFMAQ(MH, NH)                                                          \
  __builtin_amdgcn_s_setprio(1);                                               \
  _Pragma("unroll") for (int kk = 0; kk < 2; ++kk)                             \
    _Pragma("unroll") for (int lf = 0; lf < 4; ++lf)                           \
      _Pragma("unroll") for (int jj = 0; jj < 2; ++jj)                         \
        acc[(MH) * 4 + lf][(NH) * 2 + jj] =                                    \
            __builtin_amdgcn_mfma_f32_16x16x32_bf16(                           \
                af[lf][kk], bfr[jj][kk], acc[(MH) * 4 + lf][(NH) * 2 + jj],    \
                0, 0, 0);                                                      \
  __builtin_amdgcn_s_setprio(0);

#define BARRIER __builtin_amdgcn_s_barrier()
#define SCHED0  __builtin_amdgcn_sched_barrier(0)

  // Epilogue for n-tile (np0 + side*256). red = As[1] (safe: when invoked,
  // tile just read lived in buf 1 and next-tile staging targets buf 0).
#define EPILOGUE(side)                                                         \
  {                                                                            \
    __syncthreads();                                                           \
    float* red = (float*)&As[1][0];                                            \
    _Pragma("unroll") for (int mf = 0; mf < 8; ++mf) {                         \
      _Pragma("unroll") for (int pp = 0; pp < 4; ++pp) {                       \
        float tsum = 0.f;                                                      \
        _Pragma("unroll") for (int nf = 0; nf < 4; ++nf)                       \
          tsum += tanh_fast(acc[mf][nf][pp] + b1v[side][nf]) * w2v[side][nf];  \
        tsum += __shfl_xor(tsum, 1);                                           \
        tsum += __shfl_xor(tsum, 2);                                           \
        tsum += __shfl_xor(tsum, 4);                                           \
        tsum += __shfl_xor(tsum, 8);                                           \
        if (ml == 0)                                                           \
          red[wx * 256 + wm * 128 + mf * 16 + lh * 4 + pp] = tsum;             \
      }                                                                        \
    }                                                                          \
    __syncthreads();                                                           \
    if (tid < 256) {                                                           \
      float v =                                                                \
          (red[tid] + red[256 + tid]) + (red[512 + tid] + red[768 + tid]);     \
      scores2[(size_t)(m0 + tid) * 4 + ((sq & 1) * 2 + (side))] = v;           \
    }                                                                          \
  }

  // Prologue: stage tile 0 into buf 0 (A via regs, B via gload_lds).
  LOAD_A(0, 0); LOAD_A(1, 0); LOAD_A(2, 0); LOAD_A(3, 0);
  STAGE_B(0, 0, 0, 0); STAGE_B(1, 0, 0, 0);
  STAGE_B(2, 0, 0, 0); STAGE_B(3, 0, 0, 0);
  WAITV(4);   // A fp32 landed
  WRITE_A(0, 0); WRITE_A(1, 0); WRITE_A(2, 0); WRITE_A(3, 0);
  WAITV(0);   // B landed
  WAITL0;     // A ds_writes drained -> visible after barrier
  BARRIER;

  int P = 0;
  for (int tt = 0; tt < 2 * NKT - 1; ++tt) {
    const int u   = tt + 1;                       // tile being staged
    const int ktu = ((u >= NKT) ? (u - NKT) : u) << 6;
    const int nsh = (u >= NKT) ? 256 : 0;

    // Phase A: Q(0,0). Issue ALL of tile u's loads: 8 A float4 (oldest),
    // then 4 B gload_lds (newest).
    DSRA(0, P); DSRB(0, P);
    LOAD_A(0, ktu); LOAD_A(1, ktu); LOAD_A(2, ktu); LOAD_A(3, ktu);
    STAGE_B(0, P ^ 1, ktu, nsh); STAGE_B(1, P ^ 1, ktu, nsh);
    STAGE_B(2, P ^ 1, ktu, nsh); STAGE_B(3, P ^ 1, ktu, nsh);
    asm volatile("s_waitcnt lgkmcnt(8)" ::: "memory");
    BARRIER;
    WAITL0; SCHED0;
    MFMAQ(0, 0);
    BARRIER;

    // Phase B: Q(1,0) — reads A-half1 (bfr reused).
    DSRA(1, P);
    BARRIER;
    WAITL0; SCHED0;
    MFMAQ(1, 0);
    BARRIER;

    // Phase C: Q(1,1) — reads B-half1 (af reused); cvt+write A(u) to P^1.
    DSRB(1, P);
    WAITV(4);                    // 8 A-loads landed; 4 B gload_lds outstanding
    WRITE_A(0, P ^ 1); WRITE_A(1, P ^ 1);
    WRITE_A(2, P ^ 1); WRITE_A(3, P ^ 1);
    BARRIER;
    WAITL0; SCHED0;              // drains reads (for MFMA) + our A writes
    MFMAQ(1, 1);
    BARRIER;

    // Phase D: Q(0,1) — re-reads A-half0 (bfr reused).
    DSRA(0, P);
    BARRIER;
    WAITL0; SCHED0;
    MFMAQ(0, 1);
    WAITV(0);                    // B(u) landed (issued 3 phases ~2400cy ago)
    BARRIER;

    P ^= 1;

    if (tt == NKT - 1) {
      // n-tile 0 done (iter 11 read buf 1; tile 12 fully staged into buf 0).
      EPILOGUE(0);
#pragma unroll
      for (int i = 0; i < 8; ++i)
#pragma unroll
        for (int j = 0; j < 4; ++j) acc[i][j] = (f32x4)0.f;
      WAITV(0);                  // drain epilogue stores
      __syncthreads();
    }
  }

  // Drain iter (tile 23 in buf 1): no staging, all vmem already drained.
  DSRA(0, 1); DSRB(0, 1);
  asm volatile("s_waitcnt lgkmcnt(8)" ::: "memory");
  BARRIER;
  WAITL0; SCHED0;
  MFMAQ(0, 0);
  BARRIER;

  DSRA(1, 1);
  BARRIER;
  WAITL0; SCHED0;
  MFMAQ(1, 0);
  BARRIER;

  DSRB(1, 1);
  BARRIER;
  WAITL0; SCHED0;
  MFMAQ(1, 1);
  BARRIER;

  DSRA(0, 1);
  BARRIER;
  WAITL0; SCHED0;
  MFMAQ(0, 1);

  EPILOGUE(1);
}

// ---------------------------------------------------------------------------
// K2: self-sufficient aggregate. Barrier-free ballot compaction (order is
// irrelevant), sum of the 4 score partials, softmax, then fp32 gather
// weighted sum STRAIGHT FROM X (L3-resident; no Xb intermediate).
__global__ __launch_bounds__(256) void aggregate_kernel(
    const float* __restrict__ Xf, const float* __restrict__ scores2,
    const int* __restrict__ line_ids, float4* __restrict__ out4,
    float* __restrict__ out_mask) {
  __shared__ int   slist[LCAP];
  __shared__ float sw[LCAP];
  __shared__ float wred[4];
  __shared__ int   cnt_sh;
  const int seg = blockIdx.x;
  const int b = seg >> 8, lid = seg & 255;
  const int tid = threadIdx.x, lane = tid & 63, wave = tid >> 6;
  const int base = b * 4096;

  if (tid == 0) cnt_sh = 0;

  int ids[16];
#pragma unroll
  for (int c = 0; c < 16; ++c) ids[c] = line_ids[base + c * 256 + tid];
  __syncthreads();   // cnt_sh = 0 visible

#pragma unroll
  for (int c = 0; c < 16; ++c) {
    bool match = (ids[c] == lid);
    unsigned long long mask = __ballot(match);
    int cw = __popcll(mask);
    int bpos = 0;
    if (lane == 0 && cw) bpos = atomicAdd(&cnt_sh, cw);
    bpos = __shfl(bpos, 0);
    if (match) {
      int pos = bpos + __popcll(mask & ((1ull << lane) - 1ull));
      if (pos < LCAP) slist[pos] = base + c * 256 + tid;
    }
  }
  __syncthreads();
  int total = cnt_sh;
  int cnt = total > LCAP ? LCAP : total;
  if (tid == 0) out_mask[seg] = cnt > 0 ? 1.f : 0.f;
  if (cnt == 0) {
    if (tid < H_DIM / 4)
      out4[(size_t)seg * (H_DIM / 4) + tid] = make_float4(0.f, 0.f, 0.f, 0.f);
    return;
  }
  float lmax = -3.4e38f;
  if (tid < cnt) {
    const float4 a = *(const float4*)(scores2 + (size_t)slist[tid] * 4);
    float sc = (a.x + a.y) + (a.z + a.w);
    sw[tid] = sc;
    lmax = sc;
  }
#pragma unroll
  for (int d = 1; d < 64; d <<= 1) lmax = fmaxf(lmax, __shfl_xor(lmax, d));
  if (lane == 0) wred[wave] = lmax;
  __syncthreads();
  float m = fmaxf(fmaxf(wred[0], wred[1]), fmaxf(wred[2], wred[3]));
  float lsum = 0.f;
  if (tid < cnt) {
    float e = __expf(sw[tid] - m);
    sw[tid] = e;
    lsum = e;
  }
#pragma unroll
  for (int d = 1; d < 64; d <<= 1) lsum += __shfl_xor(lsum, d);
  __syncthreads();                 // wred(max) consumed before overwrite
  if (lane == 0) wred[wave] = lsum;
  __syncthreads();
  float denom = wred[0] + wred[1] + wred[2] + wred[3];
  float inv = __builtin_amdgcn_rcpf(fmaxf(denom, 1e-20f));
  if (tid < cnt) sw[tid] *= inv;
  __syncthreads();
  if (tid < H_DIM / 4) {           // 192 lanes, 16B each, coalesced per row
    const float4* xb = (const float4*)Xf + tid;  // row stride 192 float4
    float4 acc = make_float4(0.f, 0.f, 0.f, 0.f);
    int t = 0;
    for (; t + 4 <= cnt; t += 4) { // 4 independent loads in flight
      float4 u0 = xb[(size_t)slist[t]     * (H_DIM / 4)];
      float4 u1 = xb[(size_t)slist[t + 1] * (H_DIM / 4)];
      float4 u2 = xb[(size_t)slist[t + 2] * (H_DIM / 4)];
      float4 u3 = xb[(size_t)slist[t + 3] * (H_DIM / 4)];
      float w0 = sw[t], w1 = sw[t + 1], w2 = sw[t + 2], w3 = sw[t + 3];
      acc.x += w0 * u0.x + w1 * u1.x + w2 * u2.x + w3 * u3.x;
      acc.y += w0 * u0.y + w1 * u1.y + w2 * u2.y + w3 * u3.y;
      acc.z += w0 * u0.z + w1 * u1.z + w2 * u2.z + w3 * u3.z;
      acc.w += w0 * u0.w + w1 * u1.w + w2 * u2.w + w3 * u3.w;
    }
    for (; t < cnt; ++t) {
      float4 u = xb[(size_t)slist[t] * (H_DIM / 4)];
      float w = sw[t];
      acc.x += w * u.x; acc.y += w * u.y;
      acc.z += w * u.z; acc.w += w * u.w;
    }
    out4[(size_t)seg * (H_DIM / 4) + tid] = acc;
  }
}

// ---------------------------------------------------------------------------
extern "C" void kernel_launch(void* const* d_in, const int* in_sizes, int n_in,
                              void* d_out, int out_size, void* d_ws, size_t ws_size,
                              hipStream_t stream) {
  const float* X        = (const float*)d_in[0];
  const int*   line_ids = (const int*)d_in[1];
  const float* W1       = (const float*)d_in[2];
  const float* b1       = (const float*)d_in[3];
  const float* W2       = (const float*)d_in[4];
  // d_in[5] = b2: constant shift, cancels in softmax -> unused.

  char* p = (char*)d_ws;
  __hip_bfloat16* W1t     = (__hip_bfloat16*)p;  p += 1572864;
  float*          scores2 = (float*)p;           p += (size_t)M_TOK * 4 * 4;

  float* out_feats = (float*)d_out;
  float* out_mask  = out_feats + (size_t)NSEG * H_DIM;

  prep_kernel<<<768, 256, 0, stream>>>(W1, W1t);
  attn_score_kernel<<<256, 512, 0, stream>>>(X, W1t, b1, W2, scores2);
  aggregate_kernel<<<NSEG, 256, 0, stream>>>(X, scores2, line_ids,
                                             (float4*)out_feats, out_mask);
}